// Round 3
// baseline (382.548 us; speedup 1.0000x reference)
//
#include <hip/hip_runtime.h>
#include <hip/hip_bf16.h>
#include <stdint.h>
#include <stddef.h>

#define HIDDEN 4096
#define BATCH  4096
#define RANK   4

typedef _Float16 f16;
typedef __attribute__((ext_vector_type(8))) _Float16 half8;
typedef __attribute__((ext_vector_type(4))) float f32x4;
typedef __attribute__((ext_vector_type(8))) unsigned short ushort8;
typedef __attribute__((ext_vector_type(4))) unsigned short ushort4v;

// global->LDS async copy, 16B per lane. LDS dest is wave-uniform base + lane*16.
#define ASYNC_COPY16(g, l)                                                     \
  __builtin_amdgcn_global_load_lds(                                            \
      (__attribute__((address_space(1))) void*)(g),                            \
      (__attribute__((address_space(3))) void*)(l), 16, 0, 0)

// ---------------------------------------------------------------------------
// Fused prep, one dispatch:
//   blocks [0, 4096):    b_mat [K][N] f32 -> Bt [N][K] f16 (64x64 tile,
//                        f32 LDS tile stride 65: scatter phase 2-way banks = free)
//   blocks [4096, 8192): row r of x -> Xb (f16) AND hq[r][:] = h[r] @ q
__global__ __launch_bounds__(256) void prep_kernel(
    const float* __restrict__ B, f16* __restrict__ Bt,
    const float* __restrict__ x, f16* __restrict__ Xb,
    const float* __restrict__ h, const float* __restrict__ q,
    float* __restrict__ hq) {
  __shared__ float tile[64][65];  // 16.25 KB; also reused as reduce scratch
  const int id = blockIdx.x;
  const int t = threadIdx.x;

  if (id < 4096) {
    // ---- transpose+cast tile ----
    const int bx = id & 63;   // n tile
    const int by = id >> 6;   // k tile
    const int tx = t & 15, ty = t >> 4;
    #pragma unroll
    for (int i = 0; i < 4; i++) {
      const int row = ty + i * 16;  // k local
      float4 v = *(const float4*)(B + (size_t)(by * 64 + row) * HIDDEN + bx * 64 + tx * 4);
      // bank of tile[r][c] = (65r + c) % 32 = (r + c) % 32 -> scatter over
      // rows 4tx+j at fixed c: banks {4tx+j+c} = 8 distinct x 2 lanes: free.
      tile[tx * 4 + 0][row] = v.x;
      tile[tx * 4 + 1][row] = v.y;
      tile[tx * 4 + 2][row] = v.z;
      tile[tx * 4 + 3][row] = v.w;
    }
    __syncthreads();
    const int wx = t & 7, wy = t >> 3;
    #pragma unroll
    for (int i = 0; i < 2; i++) {
      const int n = wy + 32 * i;
      union { f16 hh[8]; ushort8 v; } u;
      #pragma unroll
      for (int c = 0; c < 8; c++) u.hh[c] = (f16)tile[n][wx * 8 + c];
      *(ushort8*)(Bt + (size_t)(bx * 64 + n) * HIDDEN + by * 64 + wx * 8) = u.v;
    }
  } else {
    // ---- cast x row + hq reduction for one batch row ----
    const int row = id - 4096;
    const float* hrow = h + (size_t)row * HIDDEN;
    const float* xrow = x + (size_t)row * HIDDEN;
    f16* xbrow = Xb + (size_t)row * HIDDEN;
    float a0 = 0.f, a1 = 0.f, a2 = 0.f, a3 = 0.f;
    #pragma unroll
    for (int c = 0; c < 4; c++) {
      const int k = c * 1024 + t * 4;
      const float4 hv = *(const float4*)(hrow + k);
      const float4 xv = *(const float4*)(xrow + k);
      union { f16 hh[4]; ushort4v v; } u;
      u.hh[0] = (f16)xv.x; u.hh[1] = (f16)xv.y; u.hh[2] = (f16)xv.z; u.hh[3] = (f16)xv.w;
      *(ushort4v*)(xbrow + k) = u.v;
      const float4 q0 = *(const float4*)(q + (size_t)(k + 0) * RANK);
      const float4 q1 = *(const float4*)(q + (size_t)(k + 1) * RANK);
      const float4 q2 = *(const float4*)(q + (size_t)(k + 2) * RANK);
      const float4 q3 = *(const float4*)(q + (size_t)(k + 3) * RANK);
      a0 += hv.x * q0.x + hv.y * q1.x + hv.z * q2.x + hv.w * q3.x;
      a1 += hv.x * q0.y + hv.y * q1.y + hv.z * q2.y + hv.w * q3.y;
      a2 += hv.x * q0.z + hv.y * q1.z + hv.z * q2.z + hv.w * q3.z;
      a3 += hv.x * q0.w + hv.y * q1.w + hv.z * q2.w + hv.w * q3.w;
    }
    #pragma unroll
    for (int off = 32; off; off >>= 1) {
      a0 += __shfl_down(a0, off, 64);
      a1 += __shfl_down(a1, off, 64);
      a2 += __shfl_down(a2, off, 64);
      a3 += __shfl_down(a3, off, 64);
    }
    float* red = &tile[0][0];
    const int wave = t >> 6, lane = t & 63;
    if (lane == 0) {
      red[wave * 4 + 0] = a0; red[wave * 4 + 1] = a1;
      red[wave * 4 + 2] = a2; red[wave * 4 + 3] = a3;
    }
    __syncthreads();
    if (t < 4) {
      float s = red[0 + t] + red[4 + t] + red[8 + t] + red[12 + t];
      hq[(size_t)row * RANK + t] = s;
    }
  }
}

// ---------------------------------------------------------------------------
// hq only (fallback path)
__global__ void hq_kernel(const float* __restrict__ h, const float* __restrict__ q,
                          float* __restrict__ hq) {
  const int b = blockIdx.x;
  const float* hrow = h + (size_t)b * HIDDEN;
  float a0 = 0.f, a1 = 0.f, a2 = 0.f, a3 = 0.f;
  for (int k = threadIdx.x; k < HIDDEN; k += 256) {
    float hv = hrow[k];
    float4 qv = *(const float4*)(q + (size_t)k * RANK);
    a0 += hv * qv.x; a1 += hv * qv.y; a2 += hv * qv.z; a3 += hv * qv.w;
  }
  #pragma unroll
  for (int off = 32; off; off >>= 1) {
    a0 += __shfl_down(a0, off, 64);
    a1 += __shfl_down(a1, off, 64);
    a2 += __shfl_down(a2, off, 64);
    a3 += __shfl_down(a3, off, 64);
  }
  __shared__ float red[4][4];
  const int wave = threadIdx.x >> 6, lane = threadIdx.x & 63;
  if (lane == 0) { red[wave][0] = a0; red[wave][1] = a1; red[wave][2] = a2; red[wave][3] = a3; }
  __syncthreads();
  if (threadIdx.x < 4) {
    float s = red[0][threadIdx.x] + red[1][threadIdx.x] + red[2][threadIdx.x] + red[3][threadIdx.x];
    hq[(size_t)b * RANK + threadIdx.x] = s;
  }
}

// ---------------------------------------------------------------------------
// Main GEMM: out = Xb(f16) @ Bt(f16)^T + h*(1+a) + hq @ p^T, f32 out.
// 128x128x64 tile, 4 waves, each wave 4x4 MFMA 16x16x32 tiles, 2 k-steps/iter.
// LDS layout [m][k] with XOR segment swizzle applied at the staging SOURCE
// (global_load_lds dest must stay lane-linear): LDS[m][s] holds global
// k-segment (s ^ (m&7)). Fragment reads then hit 8 distinct bank-bases per
// 16-lane phase -> 2-way (free) instead of 8-way conflicts.  [R2: conflicts=0]
#define BM 128
#define BN 128
#define BK 64

__global__ __launch_bounds__(256) void gemm_fused_kernel(
    const f16* __restrict__ Xb, const f16* __restrict__ Bt,
    const float* __restrict__ h, const float* __restrict__ a_diag,
    const float* __restrict__ p_vec, const float* __restrict__ hq,
    float* __restrict__ out) {
  __shared__ f16 As[BM * BK];  // 16 KB, row = 128 B = 8 segs x 16 B
  __shared__ f16 Bs[BN * BK];  // 16 KB
  const int tid = threadIdx.x;
  const int bm = blockIdx.x, bn = blockIdx.y;
  const int wave = tid >> 6, lane = tid & 63;
  const int wm = wave & 1, wn = wave >> 1;

  const int srow = tid >> 3;                       // 0..31
  const int sseg = (tid & 7) ^ (srow & 7);         // swizzled global k-seg
  const f16* ag = Xb + (size_t)(bm * BM + srow) * HIDDEN + sseg * 8;
  const f16* bg = Bt + (size_t)(bn * BN + srow) * HIDDEN + sseg * 8;
  char* as_base = (char*)As + wave * 1024;         // + lane*16 added by HW
  char* bs_base = (char*)Bs + wave * 1024;
  const size_t rowblk = (size_t)32 * HIDDEN;       // 32-row advance (elems)

  f32x4 acc[4][4];
  #pragma unroll
  for (int i = 0; i < 4; i++)
    #pragma unroll
    for (int j = 0; j < 4; j++)
      acc[i][j] = (f32x4){0.f, 0.f, 0.f, 0.f};

  const int q = lane >> 4;    // 0..3: k-quad within 16x16x32 fragment
  const int fm = lane & 15;   // m/n index within fragment
  const int swz = lane & 7;   // = (fragment row) & 7 for all i (16,64 = 0 mod 8)

  for (int k0 = 0; k0 < HIDDEN; k0 += BK) {
    #pragma unroll
    for (int o = 0; o < 4; o++) {
      ASYNC_COPY16(ag + o * rowblk, as_base + o * 4096);
      ASYNC_COPY16(bg + o * rowblk, bs_base + o * 4096);
    }
    ag += BK; bg += BK;
    __syncthreads();  // drains vmcnt: staged tile visible

    #pragma unroll
    for (int kk = 0; kk < 2; kk++) {
      const int sa = ((kk << 2) | q) ^ swz;  // swizzled LDS segment
      half8 af[4], bf[4];
      #pragma unroll
      for (int i = 0; i < 4; i++)
        af[i] = *(const half8*)(As + (wm * 64 + i * 16 + fm) * BK + sa * 8);
      #pragma unroll
      for (int j = 0; j < 4; j++)
        bf[j] = *(const half8*)(Bs + (wn * 64 + j * 16 + fm) * BK + sa * 8);
      #pragma unroll
      for (int i = 0; i < 4; i++)
        #pragma unroll
        for (int j = 0; j < 4; j++)
          acc[i][j] = __builtin_amdgcn_mfma_f32_16x16x32_f16(af[i], bf[j], acc[i][j], 0, 0, 0);
    }
    __syncthreads();
  }

  // epilogue: C/D layout col = lane&15, row = (lane>>4)*4 + reg  [m89/m91]
  float ad[4];
  float4 pv[4];
  #pragma unroll
  for (int j = 0; j < 4; j++) {
    const int gn = bn * BN + wn * 64 + j * 16 + fm;
    ad[j] = 1.0f + a_diag[gn];
    pv[j] = *(const float4*)(p_vec + (size_t)gn * RANK);
  }
  #pragma unroll
  for (int i = 0; i < 4; i++) {
    #pragma unroll
    for (int r = 0; r < 4; r++) {
      const size_t gb = (size_t)(bm * BM + wm * 64 + i * 16 + q * 4 + r);
      const float4 hv = *(const float4*)(hq + gb * RANK);
      const size_t rowoff = gb * HIDDEN + bn * BN + wn * 64 + fm;
      #pragma unroll
      for (int j = 0; j < 4; j++) {
        const size_t idx = rowoff + j * 16;
        const float hval = __builtin_nontemporal_load(&h[idx]);
        const float v = acc[i][j][r] + hval * ad[j] +
                        hv.x * pv[j].x + hv.y * pv[j].y + hv.z * pv[j].z + hv.w * pv[j].w;
        __builtin_nontemporal_store(v, &out[idx]);
      }
    }
  }
}

// ---------------------------------------------------------------------------
// Fallback (ws too small): straight f32 LDS-tiled GEMM + same epilogue.
__global__ void gemm_f32_fallback_kernel(const float* __restrict__ x, const float* __restrict__ bmat,
                                         const float* __restrict__ h, const float* __restrict__ a_diag,
                                         const float* __restrict__ p_vec, const float* __restrict__ hq,
                                         float* __restrict__ out) {
  __shared__ float As[16][64];
  __shared__ float Bs[16][68];
  const int t = threadIdx.x;
  const int bx = blockIdx.x, by = blockIdx.y;
  const int tm = t & 15, tn = t >> 4;
  float acc[4][4] = {{0.f}};
  for (int k0 = 0; k0 < HIDDEN; k0 += 16) {
    #pragma unroll
    for (int l = 0; l < 4; l++) {
      int idx = t + l * 256;
      int r = idx >> 4, k = idx & 15;
      As[k][r] = x[(size_t)(by * 64 + r) * HIDDEN + k0 + k];
      int kb = idx >> 6, nb = idx & 63;
      Bs[kb][nb] = bmat[(size_t)(k0 + kb) * HIDDEN + bx * 64 + nb];
    }
    __syncthreads();
    #pragma unroll
    for (int k = 0; k < 16; k++) {
      float av[4], bv[4];
      #pragma unroll
      for (int ii = 0; ii < 4; ii++) av[ii] = As[k][tm * 4 + ii];
      #pragma unroll
      for (int jj = 0; jj < 4; jj++) bv[jj] = Bs[k][tn * 4 + jj];
      #pragma unroll
      for (int ii = 0; ii < 4; ii++)
        #pragma unroll
        for (int jj = 0; jj < 4; jj++)
          acc[ii][jj] += av[ii] * bv[jj];
    }
    __syncthreads();
  }
  #pragma unroll
  for (int jj = 0; jj < 4; jj++) {
    int gn = bx * 64 + tn * 4 + jj;
    float ad = 1.0f + a_diag[gn];
    float4 pv = *(const float4*)(p_vec + (size_t)gn * RANK);
    #pragma unroll
    for (int ii = 0; ii < 4; ii++) {
      size_t gb = (size_t)(by * 64 + tm * 4 + ii);
      float4 hv = *(const float4*)(hq + gb * RANK);
      size_t idx = gb * HIDDEN + gn;
      out[idx] = acc[ii][jj] + h[idx] * ad +
                 hv.x * pv.x + hv.y * pv.y + hv.z * pv.z + hv.w * pv.w;
    }
  }
}

// ---------------------------------------------------------------------------
extern "C" void kernel_launch(void* const* d_in, const int* in_sizes, int n_in,
                              void* d_out, int out_size, void* d_ws, size_t ws_size,
                              hipStream_t stream) {
  const float* h      = (const float*)d_in[0];
  const float* x      = (const float*)d_in[1];
  const float* a_diag = (const float*)d_in[2];
  const float* p_vec  = (const float*)d_in[3];
  const float* q_vec  = (const float*)d_in[4];
  const float* b_mat  = (const float*)d_in[5];
  float* out = (float*)d_out;

  const size_t nElem = (size_t)BATCH * HIDDEN;
  const size_t hq_bytes = (size_t)BATCH * RANK * sizeof(float);       // 64 KB
  const size_t need = hq_bytes + 2 * nElem * sizeof(f16);             // + Xb + Bt

  float* hq = (float*)d_ws;

  if (ws_size >= need) {
    f16* Xb = (f16*)((char*)d_ws + hq_bytes);
    f16* Bt = Xb + nElem;
    prep_kernel<<<4096 + BATCH, 256, 0, stream>>>(b_mat, Bt, x, Xb, h, q_vec, hq);
    gemm_fused_kernel<<<dim3(BATCH / BM, HIDDEN / BN), 256, 0, stream>>>(
        Xb, Bt, h, a_diag, p_vec, hq, out);
  } else {
    hq_kernel<<<BATCH, 256, 0, stream>>>(h, q_vec, hq);
    gemm_f32_fallback_kernel<<<dim3(HIDDEN / 64, BATCH / 64), 256, 0, stream>>>(
        x, b_mat, h, a_diag, p_vec, hq, out);
  }
}